// Round 9
// baseline (260.937 us; speedup 1.0000x reference)
//
#include <hip/hip_runtime.h>
#include <hip/hip_bf16.h>

// SupernodePooling pipeline (round 9):
//   prep:    Wt/Wb = bf16(W1_top/bot)^T, Wint = Win^T
//   xcomp:   x = feat@W_in + b_in + sincos(pos) -> bf16, chunk-XOR-swizzled [N,192]
//   agemm<true>: b = x[sup] @ W1_bot + b1 -> bf16 rows in C (stride 384 elems)
//   edgepool: per 64-edge tile: gather x[src] -> MFMA @ W1_top -> +b[s] -> gelu
//             -> sum 32 rows/supernode -> g[s] f32, in place over C
//             (3-buffer depth-2 pipeline, counted vmcnt + raw barrier: 1 barrier/tile)
//   gemm192: out = g @ W2 + b2
// Identities: concat-GEMM splits; segment-mean commutes with W2; seg[e]=e/32.
// NOTE: launch_bounds generous — tight caps spilled win[]/bfr[]/acc[] to scratch
// (round-4 post-mortem: 466 MB of pure spill traffic).

#define HD 192
#define INF 16
#define N_NODES 262144
#define N_SUP 16384
#define ROWB 384      // bytes per 192-bf16 row
#define EP_TILES 8    // 64-edge tiles per edgepool block

typedef __attribute__((ext_vector_type(8))) short bf16x8;
typedef __attribute__((ext_vector_type(4))) float f32x4;

__device__ __forceinline__ unsigned f2bf(float f) {
    unsigned x = __float_as_uint(f);
    return (x + 0x7fffu + ((x >> 16) & 1u)) >> 16;   // RNE
}
__device__ __forceinline__ float bf2f(unsigned short u) {
    return __uint_as_float(((unsigned)u) << 16);
}
__device__ __forceinline__ void gload16(const void* g, void* l) {
    __builtin_amdgcn_global_load_lds(
        (const __attribute__((address_space(1))) unsigned int*)g,
        (__attribute__((address_space(3))) unsigned int*)l, 16, 0, 0);
}
// tanh-form GELU folded into accumulator: acc += gelu(v).
// max dev from exact erf-GELU ~5e-4 (validated r4-r8, absmax 0.0156)
__device__ __forceinline__ void gelu_acc(float v, float& acc) {
    const float m   = v * fmaf(v * v, -0.1029392f, -2.3021178f);
    const float den = 1.f + exp2f(m);
    const float r   = __builtin_amdgcn_rcpf(den);
    acc = fmaf(v, r, acc);
}

// ---------------------------------------------------------------------------
__global__ void prep_kernel(const float* __restrict__ W1,
                            const float* __restrict__ Win,
                            unsigned short* __restrict__ Wt,
                            unsigned short* __restrict__ Wb,
                            float* __restrict__ Wint)
{
    const int i = blockIdx.x * 256 + threadIdx.x;
    if (i < 36864) {
        const int n = i / HD, k = i % HD;
        Wt[i] = (unsigned short)f2bf(W1[k * HD + n]);
    } else if (i < 73728) {
        const int j = i - 36864;
        const int n = j / HD, k = j % HD;
        Wb[j] = (unsigned short)f2bf(W1[(size_t)(HD + k) * HD + n]);
    } else if (i < 76800) {
        const int j = i - 73728;
        const int c = j / INF, k = j % INF;
        Wint[j] = Win[k * HD + c];
    }
}

// ---------------------------------------------------------------------------
// xcomp: x[n][c] = dot(feat[n], Win[:,c]) + bin[c] + sin/cos(pos[n][c/64]*om)
// Output bf16, chunk-swizzled: 16B chunk c of row r stored at chunk c^(r&7).
// 4 groups of 64 rows per block; next group's feat/pos prefetched into regs.
// Wave-local (no barriers). Lane l owns cols {l, l+64, l+128}.
// ---------------------------------------------------------------------------
__global__ __launch_bounds__(256, 3)
void xcomp_kernel(const float* __restrict__ feat,
                  const float* __restrict__ pos,
                  const float* __restrict__ Wint,   // [192 c][16 k]
                  const float* __restrict__ bin,
                  unsigned short* __restrict__ xswz)
{
    __shared__ __align__(16) float feat_s[4][256];             // 16 rows x 16 per wave
    __shared__ float pos_s[4][48];
    __shared__ __align__(16) unsigned short dstg[4][16 * HD];  // 16 rows per wave

    const int t = threadIdx.x, w = t >> 6, l = t & 63;

    float win[3][INF];
    #pragma unroll
    for (int d = 0; d < 3; ++d)
        #pragma unroll
        for (int q = 0; q < 4; ++q)
            *reinterpret_cast<float4*>(&win[d][q * 4]) =
                *reinterpret_cast<const float4*>(Wint + (size_t)(l + 64 * d) * INF + q * 4);
    float bcol[3];
    #pragma unroll
    for (int d = 0; d < 3; ++d) bcol[d] = bin[l + 64 * d];
    const float om = exp2f(-(float)(l & 31) * 0.41524101186098287f);
    const float phase = (l < 32) ? 0.f : 1.57079632679f;   // cos = sin(+pi/2)

    int row0 = blockIdx.x * 256 + w * 16;
    float4 fstage = *reinterpret_cast<const float4*>(
        feat + (size_t)(row0 + (l >> 2)) * INF + (l & 3) * 4);
    float pstage = (l < 48) ? pos[(size_t)row0 * 3 + l] : 0.f;

    for (int gg = 0; gg < 4; ++gg) {
        *reinterpret_cast<float4*>(&feat_s[w][(l >> 2) * 16 + (l & 3) * 4]) = fstage;
        if (l < 48) pos_s[w][l] = pstage;

        const int nrow0 = row0 + 64;
        if (gg < 3) {   // prefetch next group (latency hides under compute)
            fstage = *reinterpret_cast<const float4*>(
                feat + (size_t)(nrow0 + (l >> 2)) * INF + (l & 3) * 4);
            if (l < 48) pstage = pos[(size_t)nrow0 * 3 + l];
        }

        for (int r = 0; r < 16; ++r) {
            float fr[INF];
            #pragma unroll
            for (int q = 0; q < 4; ++q)
                *reinterpret_cast<float4*>(&fr[q * 4]) =
                    *reinterpret_cast<const float4*>(&feat_s[w][r * 16 + q * 4]);
            #pragma unroll
            for (int d = 0; d < 3; ++d) {
                const float pe = __sinf(fmaf(pos_s[w][r * 3 + d], om, phase));
                float acc = bcol[d] + pe;
                #pragma unroll
                for (int k = 0; k < INF; ++k) acc = fmaf(fr[k], win[d][k], acc);
                dstg[w][r * HD + l + 64 * d] = (unsigned short)f2bf(acc);
            }
        }

        #pragma unroll
        for (int q = 0; q < 6; ++q) {
            const int id = q * 64 + l;          // 0..383
            const int rl = id / 24, c = id % 24;
            const bf16x8 v = *reinterpret_cast<const bf16x8*>(&dstg[w][rl * HD + c * 8]);
            *reinterpret_cast<bf16x8*>((char*)xswz +
                (size_t)(row0 + rl) * ROWB + ((c ^ (rl & 7)) * 16)) = v;
        }
        row0 = nrow0;
    }
}

// ---------------------------------------------------------------------------
// agemm<GATHER=true>: b = bf16( x[gidx] @ Wt^T + bias ), K=192, 64 rows/block.
// ---------------------------------------------------------------------------
template<bool GATHER>
__global__ __launch_bounds__(256, 2)
void agemm_kernel(const unsigned short* __restrict__ xswz,
                  const int* __restrict__ gidx,
                  const unsigned short* __restrict__ Wt,   // [192 n][192 k]
                  const float* __restrict__ bias,
                  unsigned short* __restrict__ outp,
                  const int out_stride,                    // elems
                  const int ntiles)
{
    __shared__ __align__(16) unsigned short xbuf[2][64 * HD];  // 2 x 24576 B
    __shared__ int nid[64];

    const int t = threadIdx.x, w = t >> 6, l = t & 63;

    bf16x8 bfr[3][6];
    #pragma unroll
    for (int ct = 0; ct < 3; ++ct) {
        const int col = w * 48 + ct * 16 + (l & 15);
        const unsigned short* wp = Wt + (size_t)col * HD + (l >> 4) * 8;
        #pragma unroll
        for (int ks = 0; ks < 6; ++ks)
            bfr[ct][ks] = *reinterpret_cast<const bf16x8*>(wp + ks * 32);
    }
    float bias_c[3] = {0.f, 0.f, 0.f};
    if (GATHER) {
        #pragma unroll
        for (int ct = 0; ct < 3; ++ct) bias_c[ct] = bias[w * 48 + ct * 16 + (l & 15)];
        if (t < 64) nid[t] = gidx[blockIdx.x * 64 + t];
        __syncthreads();
    }

    auto STAGE = [&](int tile, int buf) {
        char* lbase = (char*)&xbuf[buf][0];
        if constexpr (GATHER) {
            #pragma unroll
            for (int i = 0; i < 6; ++i) {
                const int slot = w * 64 + i * 256 + l;
                const int r = slot / 24, p = slot % 24;
                const int node = nid[r];
                const char* src = (const char*)xswz + (size_t)node * ROWB +
                                  (((p ^ (r & 7)) ^ (node & 7)) * 16);
                gload16(src, lbase + w * 1024 + i * 4096);
            }
        } else {
            const char* gb = (const char*)xswz +
                             (size_t)(blockIdx.x * ntiles + tile) * 64 * ROWB;
            #pragma unroll
            for (int i = 0; i < 6; ++i)
                gload16(gb + w * 1024 + i * 4096 + l * 16, lbase + w * 1024 + i * 4096);
        }
    };

    STAGE(0, 0);
    __syncthreads();

    for (int tt = 0; tt < ntiles; ++tt) {
        const int cur = tt & 1;
        if (tt + 1 < ntiles) STAGE(tt + 1, cur ^ 1);

        f32x4 acc[4][3];
        #pragma unroll
        for (int rt = 0; rt < 4; ++rt)
            #pragma unroll
            for (int ct = 0; ct < 3; ++ct)
                acc[rt][ct] = (f32x4){0.f, 0.f, 0.f, 0.f};

        const char* xb = (const char*)&xbuf[cur][0];
        #pragma unroll
        for (int ks = 0; ks < 6; ++ks) {
            bf16x8 af[4];
            #pragma unroll
            for (int rt = 0; rt < 4; ++rt) {
                const int row = rt * 16 + (l & 15);
                const int p = (ks * 4 + (l >> 4)) ^ (l & 7);   // row&7 == l&7
                af[rt] = *reinterpret_cast<const bf16x8*>(xb + row * ROWB + p * 16);
            }
            #pragma unroll
            for (int rt = 0; rt < 4; ++rt)
                #pragma unroll
                for (int ct = 0; ct < 3; ++ct)
                    acc[rt][ct] = __builtin_amdgcn_mfma_f32_16x16x32_bf16(
                        af[rt], bfr[ct][ks], acc[rt][ct], 0, 0, 0);
        }
        __syncthreads();   // next tile staged; all LDS reads of cur done

        char* db = (char*)&xbuf[cur][0];
        #pragma unroll
        for (int rt = 0; rt < 4; ++rt)
            #pragma unroll
            for (int ct = 0; ct < 3; ++ct) {
                const int col = w * 48 + ct * 16 + (l & 15);
                const int ch = col >> 3, off = col & 7;
                #pragma unroll
                for (int j = 0; j < 4; ++j) {
                    const int row = rt * 16 + (l >> 4) * 4 + j;
                    *reinterpret_cast<unsigned short*>(
                        db + row * ROWB + ((ch ^ (row & 7)) * 16) + off * 2) =
                        (unsigned short)f2bf(acc[rt][ct][j] + bias_c[ct]);
                }
            }
        const size_t orow0 = GATHER ? (size_t)blockIdx.x * 64
                                    : (size_t)(blockIdx.x * ntiles + tt) * 64;
        #pragma unroll
        for (int q = 0; q < 6; ++q) {
            const int id = q * 64 + l;      // 0..383
            const int rid = id / 6, cc = id % 6;
            const int c = w * 6 + cc;
            const bf16x8 v = *reinterpret_cast<const bf16x8*>(
                db + rid * ROWB + ((c ^ (rid & 7)) * 16));
            *reinterpret_cast<bf16x8*>(outp + (orow0 + rid) * out_stride + c * 8) = v;
        }
        __syncthreads();
    }
}

// ---------------------------------------------------------------------------
// edgepool (r9): 3-buffer, prefetch-depth-2, counted vmcnt + raw s_barrier.
// Per tile tt: wait vmcnt(12) [= stage(tt+1) 6 + stores(tt-1) 6 newer ops ->
// tile tt's 6 gathers provably retired], barrier, issue STAGE(tt+2), MFMA on
// buf tt%3, epilogue (gelu + shfl reduce + g store). src_idx and all 16 b-rows
// staged to LDS once at block start (no per-tile global latency hops, no
// vmcnt pollution). LDS = 73728 + 2048 + 6144 = 80 KiB -> exactly 2 blocks/CU.
// ---------------------------------------------------------------------------
__global__ __launch_bounds__(256, 2)
void edgepool_kernel(const unsigned short* __restrict__ xswz,
                     const int* __restrict__ src_idx,
                     const unsigned short* __restrict__ Wt,   // W1_top^T [192 n][192 k]
                     const unsigned short* __restrict__ bC,   // bf16 rows, stride 384 elems
                     float* __restrict__ g)                   // f32 rows, stride 192 (same mem)
{
    __shared__ __align__(16) unsigned short xbuf[3][64 * HD];  // 73728 B
    __shared__ int sIdx[EP_TILES * 64];                        //  2048 B
    __shared__ unsigned short bs[EP_TILES * 2 * HD];           //  6144 B

    const int t = threadIdx.x, w = t >> 6, l = t & 63;

    // src indices for all 8 tiles (coalesced)
    #pragma unroll
    for (int i = 0; i < (EP_TILES * 64) / 256; ++i)
        sIdx[t + i * 256] = src_idx[(size_t)blockIdx.x * (EP_TILES * 64) + t + i * 256];
    // b rows for this block's 16 supernodes (192 ushorts each)
    {
        const size_t srow0 = (size_t)blockIdx.x * (EP_TILES * 2);
        #pragma unroll
        for (int i = 0; i < 6; ++i) {             // 1536 uints / 256 thr
            const int idx = t + i * 256;
            const int r = idx / 96, c = idx % 96; // 96 uints per row
            reinterpret_cast<unsigned*>(bs)[idx] =
                *reinterpret_cast<const unsigned*>(bC + (srow0 + r) * 384 + c * 2);
        }
    }

    bf16x8 bfr[3][6];
    #pragma unroll
    for (int ct = 0; ct < 3; ++ct) {
        const int col = w * 48 + ct * 16 + (l & 15);
        const unsigned short* wp = Wt + (size_t)col * HD + (l >> 4) * 8;
        #pragma unroll
        for (int ks = 0; ks < 6; ++ks)
            bfr[ct][ks] = *reinterpret_cast<const bf16x8*>(wp + ks * 32);
    }

    // per-thread constant slot decomposition for the gather
    int rr[6], pp[6];
    #pragma unroll
    for (int i = 0; i < 6; ++i) {
        const int slot = w * 64 + i * 256 + l;
        rr[i] = slot / 24; pp[i] = slot % 24;
    }

    __syncthreads();   // sIdx/bs ready; drains staging loads -> clean vmcnt ledger

    auto STAGE = [&](int tile, int buf) {
        char* lbase = (char*)&xbuf[buf][0] + w * 1024;
        const int* se = &sIdx[tile * 64];
        #pragma unroll
        for (int i = 0; i < 6; ++i) {
            const int node = se[rr[i]];
            const char* src = (const char*)xswz + (size_t)node * ROWB +
                              (((pp[i] ^ (rr[i] & 7)) ^ (node & 7)) * 16);
            gload16(src, lbase + i * 4096);
        }
    };

    STAGE(0, 0);
    STAGE(1, 1);

    #pragma unroll 1
    for (int tt = 0; tt < EP_TILES; ++tt) {
        // tile tt's 6 gathers are older than: stage(tt+1)=6 (+ stores(tt-1)=6 for tt>0)
        if (tt == 0) { asm volatile("s_waitcnt vmcnt(6)" ::: "memory"); }
        else         { asm volatile("s_waitcnt vmcnt(12)" ::: "memory"); }
        __builtin_amdgcn_s_barrier();
        __builtin_amdgcn_sched_barrier(0);

        if (tt + 2 < EP_TILES) STAGE(tt + 2, (tt + 2) % 3);

        f32x4 acc[4][3];
        #pragma unroll
        for (int rt = 0; rt < 4; ++rt)
            #pragma unroll
            for (int ct = 0; ct < 3; ++ct)
                acc[rt][ct] = (f32x4){0.f, 0.f, 0.f, 0.f};

        const char* xb = (const char*)&xbuf[tt % 3][0];
        #pragma unroll
        for (int ks = 0; ks < 6; ++ks) {
            bf16x8 af[4];
            #pragma unroll
            for (int rt = 0; rt < 4; ++rt) {
                const int row = rt * 16 + (l & 15);
                const int p = (ks * 4 + (l >> 4)) ^ (l & 7);   // row&7 == l&7
                af[rt] = *reinterpret_cast<const bf16x8*>(xb + row * ROWB + p * 16);
            }
            #pragma unroll
            for (int rt = 0; rt < 4; ++rt)
                #pragma unroll
                for (int ct = 0; ct < 3; ++ct)
                    acc[rt][ct] = __builtin_amdgcn_mfma_f32_16x16x32_bf16(
                        af[rt], bfr[ct][ks], acc[rt][ct], 0, 0, 0);
        }

        // epilogue: +b (from LDS), gelu, 32-row column reduce, write g
        const int s0l = tt * 2;
        #pragma unroll
        for (int sn = 0; sn < 2; ++sn)
            #pragma unroll
            for (int ct = 0; ct < 3; ++ct) {
                const float bval = bf2f(bs[(s0l + sn) * HD + w * 48 + ct * 16 + (l & 15)]);
                float part = 0.f;
                #pragma unroll
                for (int r2 = 0; r2 < 2; ++r2)
                    #pragma unroll
                    for (int j = 0; j < 4; ++j)
                        gelu_acc(acc[sn * 2 + r2][ct][j] + bval, part);
                part += __shfl_xor(part, 16);
                part += __shfl_xor(part, 32);
                if (l < 16)
                    g[((size_t)blockIdx.x * (EP_TILES * 2) + s0l + sn) * HD +
                      w * 48 + ct * 16 + l] = part * 0.03125f;
            }
    }
}

// ---------------------------------------------------------------------------
// out = A[rows,192] @ W[192,192] + bias   (f32)
// ---------------------------------------------------------------------------
__global__ __launch_bounds__(256, 2)
void gemm192_kernel(const float* __restrict__ A,
                    const float* __restrict__ W,
                    const float* __restrict__ bias,
                    float* __restrict__ out)
{
    __shared__ float xsf[64][196];
    __shared__ float wchunk[32][HD];
    const int t    = threadIdx.x;
    const int row0 = blockIdx.x * 64;

    const float4* ap = reinterpret_cast<const float4*>(A + (size_t)row0 * HD);
    #pragma unroll
    for (int q = 0; q < 12; ++q) {
        const int f4 = t + q * 256;
        const int r = f4 / 48, c = f4 % 48;
        *reinterpret_cast<float4*>(&xsf[r][c * 4]) = ap[f4];
    }

    const int tr = t >> 4;
    const int tc = t & 15;
    float acc[4][12];
    #pragma unroll
    for (int i = 0; i < 4; ++i)
        #pragma unroll
        for (int j = 0; j < 12; ++j) acc[i][j] = 0.f;

    for (int kc = 0; kc < 6; ++kc) {
        __syncthreads();
        {
            const float4* wp = reinterpret_cast<const float4*>(W + kc * 32 * HD);
            float4* wsp = reinterpret_cast<float4*>(&wchunk[0][0]);
            #pragma unroll
            for (int q = 0; q < 6; ++q) wsp[t + q * 256] = wp[t + q * 256];
        }
        __syncthreads();
        #pragma unroll 4
        for (int k = 0; k < 32; ++k) {
            const int kg = kc * 32 + k;
            float xv[4];
            #pragma unroll
            for (int i = 0; i < 4; ++i) xv[i] = xsf[tr * 4 + i][kg];
            float wv[12];
            #pragma unroll
            for (int j4 = 0; j4 < 3; ++j4)
                *reinterpret_cast<float4*>(&wv[j4 * 4]) =
                    *reinterpret_cast<const float4*>(&wchunk[k][tc * 12 + j4 * 4]);
            #pragma unroll
            for (int i = 0; i < 4; ++i)
                #pragma unroll
                for (int j = 0; j < 12; ++j)
                    acc[i][j] = fmaf(xv[i], wv[j], acc[i][j]);
        }
    }

    float bb[12];
    #pragma unroll
    for (int j = 0; j < 12; ++j) bb[j] = bias[tc * 12 + j];

    #pragma unroll
    for (int i = 0; i < 4; ++i) {
        float* o = out + (size_t)(row0 + tr * 4 + i) * HD + tc * 12;
        #pragma unroll
        for (int j4 = 0; j4 < 3; ++j4) {
            float4 v;
            v.x = acc[i][j4 * 4 + 0] + bb[j4 * 4 + 0];
            v.y = acc[i][j4 * 4 + 1] + bb[j4 * 4 + 1];
            v.z = acc[i][j4 * 4 + 2] + bb[j4 * 4 + 2];
            v.w = acc[i][j4 * 4 + 3] + bb[j4 * 4 + 3];
            *reinterpret_cast<float4*>(o + j4 * 4) = v;
        }
    }
}

extern "C" void kernel_launch(void* const* d_in, const int* in_sizes, int n_in,
                              void* d_out, int out_size, void* d_ws, size_t ws_size,
                              hipStream_t stream)
{
    const float* feat = (const float*)d_in[0];
    const float* pos  = (const float*)d_in[1];
    const int*   sup  = (const int*)d_in[2];
    const int*   src  = (const int*)d_in[4];
    const float* Win  = (const float*)d_in[6];
    const float* bin  = (const float*)d_in[7];
    const float* W1   = (const float*)d_in[8];   // [384,192]
    const float* b1   = (const float*)d_in[9];
    const float* W2   = (const float*)d_in[10];  // [192,192]
    const float* b2   = (const float*)d_in[11];

    char* ws = (char*)d_ws;
    unsigned short* Wt   = (unsigned short*)ws;              //  73728 B
    unsigned short* Wb   = (unsigned short*)(ws + 73728);    //  73728 B
    float*          Wint = (float*)(ws + 147456);            //  12288 B
    unsigned short* x    = (unsigned short*)(ws + 159744);   // 100663296 B
    char*           C    = ws + 159744 + 100663296;          //  12582912 B
    float* out = (float*)d_out;

    prep_kernel<<<300, 256, 0, stream>>>(W1, Win, Wt, Wb, Wint);
    // x (bf16, chunk-swizzled), 1024 blocks x 256 rows
    xcomp_kernel<<<N_NODES / 256, 256, 0, stream>>>(feat, pos, Wint, bin, x);
    // b = x[sup] @ W1_bot + b1 -> bf16 rows in C (stride 384 elems)
    agemm_kernel<true><<<N_SUP / 64, 256, 0, stream>>>(
        x, sup, Wb, b1, (unsigned short*)C, 384, 1);
    // g = segment-mean(gelu(x[src]@W1_top + b)) -> f32 in place over C
    edgepool_kernel<<<N_SUP / (2 * EP_TILES), 256, 0, stream>>>(
        x, src, Wt, (const unsigned short*)C, (float*)C);
    // out = g @ W2 + b2
    gemm192_kernel<<<N_SUP / 64, 256, 0, stream>>>((const float*)C, W2, b2, out);
}

// Round 10
// 257.307 us; speedup vs baseline: 1.0141x; 1.0141x over previous
//
#include <hip/hip_runtime.h>
#include <hip/hip_bf16.h>

// SupernodePooling pipeline (round 10: x is NEVER materialized):
//   prep:    Wt/Wb = bf16(W1_top/bot)^T, Wint = Win^T
//   bcomp:   gather feat/pos[sup] -> compute x tile -> MFMA @ W1_bot + b1
//            -> bf16 b rows into C (stride 384 elems)            [256 blocks]
//   fusepool: per 64-edge tile: gather feat/pos[src] -> compute x (bf16,
//            XOR-swizzled, double-buffered LDS) -> MFMA @ W1_top -> +b[s]
//            -> gelu -> sum 32 rows/supernode -> g[s] f32 in place over C
//   gemm192: out = g @ W2 + b2
// Identities: concat-GEMM splits; segment-mean commutes with W2; seg[e]=e/32.
// Rationale (r9 post-mortem): gathering x cost 384 B/edge (96 MB HBM);
// feat+pos are 76 B/edge and L2/L3-resident (feat 16.8 MB, pos 3.1 MB).
// Recompute x per edge-tile: 2x x-compute VALU, overlapped with MFMA pipe.
// NOTE: launch_bounds (256,2) — tighter caps spilled to scratch (r4: 466 MB).

#define HD 192
#define INF 16
#define N_NODES 262144
#define N_SUP 16384
#define EP_TILES 8    // 64-edge tiles per fusepool block

typedef __attribute__((ext_vector_type(8))) short bf16x8;
typedef __attribute__((ext_vector_type(4))) float f32x4;

__device__ __forceinline__ unsigned f2bf(float f) {
    unsigned x = __float_as_uint(f);
    return (x + 0x7fffu + ((x >> 16) & 1u)) >> 16;   // RNE
}
__device__ __forceinline__ float bf2f(unsigned short u) {
    return __uint_as_float(((unsigned)u) << 16);
}
// tanh-form GELU folded into accumulator: acc += gelu(v).
// max dev from exact erf-GELU ~5e-4 (validated r4-r9, absmax 0.0156)
__device__ __forceinline__ void gelu_acc(float v, float& acc) {
    const float m   = v * fmaf(v * v, -0.1029392f, -2.3021178f);
    const float den = 1.f + exp2f(m);
    const float r   = __builtin_amdgcn_rcpf(den);
    acc = fmaf(v, r, acc);
}

// ---------------------------------------------------------------------------
__global__ void prep_kernel(const float* __restrict__ W1,
                            const float* __restrict__ Win,
                            unsigned short* __restrict__ Wt,
                            unsigned short* __restrict__ Wb,
                            float* __restrict__ Wint)
{
    const int i = blockIdx.x * 256 + threadIdx.x;
    if (i < 36864) {
        const int n = i / HD, k = i % HD;
        Wt[i] = (unsigned short)f2bf(W1[k * HD + n]);
    } else if (i < 73728) {
        const int j = i - 36864;
        const int n = j / HD, k = j % HD;
        Wb[j] = (unsigned short)f2bf(W1[(size_t)(HD + k) * HD + n]);
    } else if (i < 76800) {
        const int j = i - 73728;
        const int c = j / INF, k = j % INF;
        Wint[j] = Win[k * HD + c];
    }
}

// ---------------------------------------------------------------------------
// bcomp: b = bf16( x[sup] @ W1_bot^T + b1 ) -> C rows (stride 384 elems).
// One 64-row tile per block. x computed in-kernel from gathered feat/pos
// (xcomp's per-wave pattern: wave w owns rows w*16..+15, lane l cols
// {l,l+64,l+128}), written bf16 XOR-swizzled to LDS, then agemm's MFMA +
// D-stage epilogue (proven verbatim).
// ---------------------------------------------------------------------------
__global__ __launch_bounds__(256, 2)
void bcomp_kernel(const float* __restrict__ feat,
                  const float* __restrict__ pos,
                  const int*   __restrict__ sup,
                  const float* __restrict__ Wint,   // [192 c][16 k]
                  const float* __restrict__ bin,
                  const unsigned short* __restrict__ Wb,  // [192 n][192 k]
                  const float* __restrict__ b1,
                  unsigned short* __restrict__ outp)      // stride 384 elems
{
    __shared__ __align__(16) unsigned short xs[2][64 * HD];  // [0]=A, [1]=D-stage
    __shared__ __align__(16) float feat_s[4][256];
    __shared__ float pos_s[4][48];
    __shared__ int nid[64];

    const int t = threadIdx.x, w = t >> 6, l = t & 63;

    if (t < 64) nid[t] = sup[blockIdx.x * 64 + t];

    // persistent per-lane x-weights + B-frags
    float win[3][INF];
    #pragma unroll
    for (int d = 0; d < 3; ++d)
        #pragma unroll
        for (int q = 0; q < 4; ++q)
            *reinterpret_cast<float4*>(&win[d][q * 4]) =
                *reinterpret_cast<const float4*>(Wint + (size_t)(l + 64 * d) * INF + q * 4);
    float bcol[3];
    #pragma unroll
    for (int d = 0; d < 3; ++d) bcol[d] = bin[l + 64 * d];
    const float om = exp2f(-(float)(l & 31) * 0.41524101186098287f);
    const float phase = (l < 32) ? 0.f : 1.57079632679f;

    bf16x8 bfr[3][6];
    #pragma unroll
    for (int ct = 0; ct < 3; ++ct) {
        const int col = w * 48 + ct * 16 + (l & 15);
        const unsigned short* wp = Wb + (size_t)col * HD + (l >> 4) * 8;
        #pragma unroll
        for (int ks = 0; ks < 6; ++ks)
            bfr[ct][ks] = *reinterpret_cast<const bf16x8*>(wp + ks * 32);
    }
    float bias_c[3];
    #pragma unroll
    for (int ct = 0; ct < 3; ++ct) bias_c[ct] = b1[w * 48 + ct * 16 + (l & 15)];

    __syncthreads();   // nid ready

    // gather feat/pos (wave w -> rows w*16..+15), stage wave-local
    {
        const int nf = nid[w * 16 + (l >> 2)];
        const float4 fs = *reinterpret_cast<const float4*>(
            feat + (size_t)nf * INF + (l & 3) * 4);
        *reinterpret_cast<float4*>(&feat_s[w][(l >> 2) * 16 + (l & 3) * 4]) = fs;
        if (l < 48) {
            const int np = nid[w * 16 + l / 3];
            pos_s[w][l] = pos[(size_t)np * 3 + (l % 3)];
        }
    }

    // compute x rows -> xs[0] (bf16, XOR-swizzled: col c of row n at chunk (c>>3)^(n&7))
    for (int r = 0; r < 16; ++r) {
        const int n = w * 16 + r;
        float fr[INF];
        #pragma unroll
        for (int q = 0; q < 4; ++q)
            *reinterpret_cast<float4*>(&fr[q * 4]) =
                *reinterpret_cast<const float4*>(&feat_s[w][r * 16 + q * 4]);
        #pragma unroll
        for (int d = 0; d < 3; ++d) {
            const float pe = __sinf(fmaf(pos_s[w][r * 3 + d], om, phase));
            float acc = bcol[d] + pe;
            #pragma unroll
            for (int k = 0; k < INF; ++k) acc = fmaf(fr[k], win[d][k], acc);
            *reinterpret_cast<unsigned short*>(
                (char*)&xs[0][0] + n * 384 +
                ((((l >> 3) + 8 * d) ^ (r & 7)) * 16) + (l & 7) * 2) =
                (unsigned short)f2bf(acc);
        }
    }
    __syncthreads();   // xs[0] ready

    f32x4 acc[4][3];
    #pragma unroll
    for (int rt = 0; rt < 4; ++rt)
        #pragma unroll
        for (int ct = 0; ct < 3; ++ct)
            acc[rt][ct] = (f32x4){0.f, 0.f, 0.f, 0.f};

    const char* xb = (const char*)&xs[0][0];
    #pragma unroll
    for (int ks = 0; ks < 6; ++ks) {
        bf16x8 af[4];
        #pragma unroll
        for (int rt = 0; rt < 4; ++rt) {
            const int row = rt * 16 + (l & 15);
            const int p = (ks * 4 + (l >> 4)) ^ (l & 7);   // row&7 == l&7
            af[rt] = *reinterpret_cast<const bf16x8*>(xb + row * 384 + p * 16);
        }
        #pragma unroll
        for (int rt = 0; rt < 4; ++rt)
            #pragma unroll
            for (int ct = 0; ct < 3; ++ct)
                acc[rt][ct] = __builtin_amdgcn_mfma_f32_16x16x32_bf16(
                    af[rt], bfr[ct][ks], acc[rt][ct], 0, 0, 0);
    }

    // D (+b1) -> xs[1] (XOR-swizzled), then coalesced bf16 store (agemm verbatim)
    char* db = (char*)&xs[1][0];
    #pragma unroll
    for (int rt = 0; rt < 4; ++rt)
        #pragma unroll
        for (int ct = 0; ct < 3; ++ct) {
            const int col = w * 48 + ct * 16 + (l & 15);
            const int ch = col >> 3, off = col & 7;
            #pragma unroll
            for (int j = 0; j < 4; ++j) {
                const int row = rt * 16 + (l >> 4) * 4 + j;
                *reinterpret_cast<unsigned short*>(
                    db + row * 384 + ((ch ^ (row & 7)) * 16) + off * 2) =
                    (unsigned short)f2bf(acc[rt][ct][j] + bias_c[ct]);
            }
        }
    __syncthreads();
    const size_t orow0 = (size_t)blockIdx.x * 64;
    #pragma unroll
    for (int q = 0; q < 6; ++q) {
        const int id = q * 64 + l;
        const int rid = id / 6, cc = id % 6;
        const int c = w * 6 + cc;
        const bf16x8 v = *reinterpret_cast<const bf16x8*>(
            db + rid * 384 + ((c ^ (rid & 7)) * 16));
        *reinterpret_cast<bf16x8*>(outp + (orow0 + rid) * 384 + c * 8) = v;
    }
}

// ---------------------------------------------------------------------------
// fusepool: per 64-edge tile (2 supernodes):
//   gather feat/pos[src] (regs, prefetched 1 tile ahead) -> compute x (bf16,
//   XOR-swizzled) into xs[tile&1] -> MFMA @ W1_top -> +b (bs LDS) -> gelu ->
//   shfl_xor(16)+shfl_xor(32) 32-row column sum -> g[s] = part/32 (over C).
// ONE barrier per tile; compute(tt+1) and MFMA(tt) share the barrier-free
// region (disjoint xs buffers; hazard proof: xs[p] written at compute(tt),
// read at MFMA(tt) after bar(tt); rewritten at compute(tt+2) which follows
// bar(tt+1), and every wave's MFMA(tt) precedes its bar(tt+1)).
// ---------------------------------------------------------------------------
__global__ __launch_bounds__(256, 2)
void fusepool_kernel(const float* __restrict__ feat,
                     const float* __restrict__ pos,
                     const int* __restrict__ src_idx,
                     const float* __restrict__ Wint,
                     const float* __restrict__ bin,
                     const unsigned short* __restrict__ Wt,   // [192 n][192 k]
                     const unsigned short* __restrict__ bC,   // bf16, stride 384 elems
                     float* __restrict__ g)                   // f32, stride 192 (same mem)
{
    __shared__ __align__(16) unsigned short xs[2][64 * HD];  // 49152 B
    __shared__ __align__(16) float feat_s[4][256];           //  4096 B
    __shared__ float pos_s[4][48];                           //   768 B
    __shared__ int sIdx[EP_TILES * 64];                      //  2048 B
    __shared__ unsigned short bs[EP_TILES * 2 * HD];         //  6144 B

    const int t = threadIdx.x, w = t >> 6, l = t & 63;

    // block-start staging: src indices + this block's 16 b-rows
    #pragma unroll
    for (int i = 0; i < (EP_TILES * 64) / 256; ++i)
        sIdx[t + i * 256] = src_idx[(size_t)blockIdx.x * (EP_TILES * 64) + t + i * 256];
    {
        const size_t srow0 = (size_t)blockIdx.x * (EP_TILES * 2);
        #pragma unroll
        for (int i = 0; i < 6; ++i) {
            const int idx = t + i * 256;
            const int r = idx / 96, c = idx % 96;
            reinterpret_cast<unsigned*>(bs)[idx] =
                *reinterpret_cast<const unsigned*>(bC + (srow0 + r) * 384 + c * 2);
        }
    }

    // persistent per-lane x-weights + B-frags
    float win[3][INF];
    #pragma unroll
    for (int d = 0; d < 3; ++d)
        #pragma unroll
        for (int q = 0; q < 4; ++q)
            *reinterpret_cast<float4*>(&win[d][q * 4]) =
                *reinterpret_cast<const float4*>(Wint + (size_t)(l + 64 * d) * INF + q * 4);
    float bcol[3];
    #pragma unroll
    for (int d = 0; d < 3; ++d) bcol[d] = bin[l + 64 * d];
    const float om = exp2f(-(float)(l & 31) * 0.41524101186098287f);
    const float phase = (l < 32) ? 0.f : 1.57079632679f;

    bf16x8 bfr[3][6];
    #pragma unroll
    for (int ct = 0; ct < 3; ++ct) {
        const int col = w * 48 + ct * 16 + (l & 15);
        const unsigned short* wp = Wt + (size_t)col * HD + (l >> 4) * 8;
        #pragma unroll
        for (int ks = 0; ks < 6; ++ks)
            bfr[ct][ks] = *reinterpret_cast<const bf16x8*>(wp + ks * 32);
    }

    __syncthreads();   // sIdx/bs ready

    // gather loads for a tile (regs): wave w -> rows w*16..+15
    auto LOADT = [&](int tile, float4& fs, float& ps) {
        const int nf = sIdx[tile * 64 + w * 16 + (l >> 2)];
        fs = *reinterpret_cast<const float4*>(feat + (size_t)nf * INF + (l & 3) * 4);
        if (l < 48) {
            const int np = sIdx[tile * 64 + w * 16 + l / 3];
            ps = pos[(size_t)np * 3 + (l % 3)];
        }
    };
    // compute x for one tile into xb (bf16, XOR-swizzled)
    auto COMPUTE = [&](unsigned short* xbuf, float4 fs, float ps) {
        *reinterpret_cast<float4*>(&feat_s[w][(l >> 2) * 16 + (l & 3) * 4]) = fs;
        if (l < 48) pos_s[w][l] = ps;
        for (int r = 0; r < 16; ++r) {
            const int n = w * 16 + r;
            float fr[INF];
            #pragma unroll
            for (int q = 0; q < 4; ++q)
                *reinterpret_cast<float4*>(&fr[q * 4]) =
                    *reinterpret_cast<const float4*>(&feat_s[w][r * 16 + q * 4]);
            #pragma unroll
            for (int d = 0; d < 3; ++d) {
                const float pe = __sinf(fmaf(pos_s[w][r * 3 + d], om, phase));
                float acc = bcol[d] + pe;
                #pragma unroll
                for (int k = 0; k < INF; ++k) acc = fmaf(fr[k], win[d][k], acc);
                *reinterpret_cast<unsigned short*>(
                    (char*)xbuf + n * 384 +
                    ((((l >> 3) + 8 * d) ^ (r & 7)) * 16) + (l & 7) * 2) =
                    (unsigned short)f2bf(acc);
            }
        }
    };

    // prologue
    float4 fstage; float pstage = 0.f;
    LOADT(0, fstage, pstage);
    COMPUTE(&xs[0][0], fstage, pstage);
    if (EP_TILES > 1) LOADT(1, fstage, pstage);

    #pragma unroll 1
    for (int tt = 0; tt < EP_TILES; ++tt) {
        __syncthreads();   // xs[tt&1] ready for all waves

        // next tile's x-compute (disjoint buffer) — interleaves with MFMA below
        if (tt + 1 < EP_TILES) {
            COMPUTE(&xs[(tt + 1) & 1][0], fstage, pstage);
            if (tt + 2 < EP_TILES) LOADT(tt + 2, fstage, pstage);
        }

        f32x4 acc[4][3];
        #pragma unroll
        for (int rt = 0; rt < 4; ++rt)
            #pragma unroll
            for (int ct = 0; ct < 3; ++ct)
                acc[rt][ct] = (f32x4){0.f, 0.f, 0.f, 0.f};

        const char* xb = (const char*)&xs[tt & 1][0];
        #pragma unroll
        for (int ks = 0; ks < 6; ++ks) {
            bf16x8 af[4];
            #pragma unroll
            for (int rt = 0; rt < 4; ++rt) {
                const int row = rt * 16 + (l & 15);
                const int p = (ks * 4 + (l >> 4)) ^ (l & 7);   // row&7 == l&7
                af[rt] = *reinterpret_cast<const bf16x8*>(xb + row * 384 + p * 16);
            }
            #pragma unroll
            for (int rt = 0; rt < 4; ++rt)
                #pragma unroll
                for (int ct = 0; ct < 3; ++ct)
                    acc[rt][ct] = __builtin_amdgcn_mfma_f32_16x16x32_bf16(
                        af[rt], bfr[ct][ks], acc[rt][ct], 0, 0, 0);
        }

        // epilogue: +b (LDS), gelu, 32-row column reduce, store g
        const int s0l = tt * 2;
        #pragma unroll
        for (int sn = 0; sn < 2; ++sn)
            #pragma unroll
            for (int ct = 0; ct < 3; ++ct) {
                const float bval = bf2f(bs[(s0l + sn) * HD + w * 48 + ct * 16 + (l & 15)]);
                float part = 0.f;
                #pragma unroll
                for (int r2 = 0; r2 < 2; ++r2)
                    #pragma unroll
                    for (int j = 0; j < 4; ++j)
                        gelu_acc(acc[sn * 2 + r2][ct][j] + bval, part);
                part += __shfl_xor(part, 16);
                part += __shfl_xor(part, 32);
                if (l < 16)
                    g[((size_t)blockIdx.x * (EP_TILES * 2) + s0l + sn) * HD +
                      w * 48 + ct * 16 + l] = part * 0.03125f;
            }
    }
}

// ---------------------------------------------------------------------------
// out = A[rows,192] @ W[192,192] + bias   (f32)
// ---------------------------------------------------------------------------
__global__ __launch_bounds__(256, 2)
void gemm192_kernel(const float* __restrict__ A,
                    const float* __restrict__ W,
                    const float* __restrict__ bias,
                    float* __restrict__ out)
{
    __shared__ float xsf[64][196];
    __shared__ float wchunk[32][HD];
    const int t    = threadIdx.x;
    const int row0 = blockIdx.x * 64;

    const float4* ap = reinterpret_cast<const float4*>(A + (size_t)row0 * HD);
    #pragma unroll
    for (int q = 0; q < 12; ++q) {
        const int f4 = t + q * 256;
        const int r = f4 / 48, c = f4 % 48;
        *reinterpret_cast<float4*>(&xsf[r][c * 4]) = ap[f4];
    }

    const int tr = t >> 4;
    const int tc = t & 15;
    float acc[4][12];
    #pragma unroll
    for (int i = 0; i < 4; ++i)
        #pragma unroll
        for (int j = 0; j < 12; ++j) acc[i][j] = 0.f;

    for (int kc = 0; kc < 6; ++kc) {
        __syncthreads();
        {
            const float4* wp = reinterpret_cast<const float4*>(W + kc * 32 * HD);
            float4* wsp = reinterpret_cast<float4*>(&wchunk[0][0]);
            #pragma unroll
            for (int q = 0; q < 6; ++q) wsp[t + q * 256] = wp[t + q * 256];
        }
        __syncthreads();
        #pragma unroll 4
        for (int k = 0; k < 32; ++k) {
            const int kg = kc * 32 + k;
            float xv[4];
            #pragma unroll
            for (int i = 0; i < 4; ++i) xv[i] = xsf[tr * 4 + i][kg];
            float wv[12];
            #pragma unroll
            for (int j4 = 0; j4 < 3; ++j4)
                *reinterpret_cast<float4*>(&wv[j4 * 4]) =
                    *reinterpret_cast<const float4*>(&wchunk[k][tc * 12 + j4 * 4]);
            #pragma unroll
            for (int i = 0; i < 4; ++i)
                #pragma unroll
                for (int j = 0; j < 12; ++j)
                    acc[i][j] = fmaf(xv[i], wv[j], acc[i][j]);
        }
    }

    float bb[12];
    #pragma unroll
    for (int j = 0; j < 12; ++j) bb[j] = bias[tc * 12 + j];

    #pragma unroll
    for (int i = 0; i < 4; ++i) {
        float* o = out + (size_t)(row0 + tr * 4 + i) * HD + tc * 12;
        #pragma unroll
        for (int j4 = 0; j4 < 3; ++j4) {
            float4 v;
            v.x = acc[i][j4 * 4 + 0] + bb[j4 * 4 + 0];
            v.y = acc[i][j4 * 4 + 1] + bb[j4 * 4 + 1];
            v.z = acc[i][j4 * 4 + 2] + bb[j4 * 4 + 2];
            v.w = acc[i][j4 * 4 + 3] + bb[j4 * 4 + 3];
            *reinterpret_cast<float4*>(o + j4 * 4) = v;
        }
    }
}

extern "C" void kernel_launch(void* const* d_in, const int* in_sizes, int n_in,
                              void* d_out, int out_size, void* d_ws, size_t ws_size,
                              hipStream_t stream)
{
    const float* feat = (const float*)d_in[0];
    const float* pos  = (const float*)d_in[1];
    const int*   sup  = (const int*)d_in[2];
    const int*   src  = (const int*)d_in[4];
    const float* Win  = (const float*)d_in[6];
    const float* bin  = (const float*)d_in[7];
    const float* W1   = (const float*)d_in[8];   // [384,192]
    const float* b1   = (const float*)d_in[9];
    const float* W2   = (const float*)d_in[10];  // [192,192]
    const float* b2   = (const float*)d_in[11];

    char* ws = (char*)d_ws;
    unsigned short* Wt   = (unsigned short*)ws;              //  73728 B
    unsigned short* Wb   = (unsigned short*)(ws + 73728);    //  73728 B
    float*          Wint = (float*)(ws + 147456);            //  12288 B
    char*           C    = ws + 159744;                      //  12582912 B
    float* out = (float*)d_out;

    prep_kernel<<<300, 256, 0, stream>>>(W1, Win, Wt, Wb, Wint);
    // b = x[sup] @ W1_bot + b1 -> bf16 rows in C (stride 384 elems)
    bcomp_kernel<<<N_SUP / 64, 256, 0, stream>>>(
        feat, pos, sup, Wint, bin, Wb, b1, (unsigned short*)C);
    // g = segment-mean(gelu(x[src]@W1_top + b)) -> f32 in place over C
    fusepool_kernel<<<N_SUP / (2 * EP_TILES), 256, 0, stream>>>(
        feat, pos, src, Wint, bin, Wt, (const unsigned short*)C, (float*)C);
    // out = g @ W2 + b2
    gemm192_kernel<<<N_SUP / 64, 256, 0, stream>>>((const float*)C, W2, b2, out);
}

// Round 11
// 217.005 us; speedup vs baseline: 1.2024x; 1.1857x over previous
//
#include <hip/hip_runtime.h>
#include <hip/hip_bf16.h>

// SupernodePooling (round 11: x-recompute moved onto the MFMA pipe):
//   a_edge = [PE(pos) | feat] @ [[W1t];[Win@W1t]] + (bin@W1t)        K = 224
//   b      = [PE | feat][sup] @ [[W1b];[Win@W1b]] + (bin@W1b + b1)   (bcomp)
//   g[s]   = mean_32 gelu(a_edge + b[s])   -> f32 in place over C    (fusepool)
//   out    = g @ W2 + b2                                             (gemm192)
// Identities: concat-GEMM splits; segment-mean commutes with W2; seg[e]=e/32;
// x@W1t = feat@(Win@W1t) + sincos(pos)@W1t + bin@W1t  (associativity).
// r10 post-mortem: VALU-bound (77% busy) on feat@Win scalar FMAs; this round
// precomputes Win@W1{t,b} [16x192] in prep and extends MFMA K to 224.

#define HD 192
#define INF 16
#define N_SUP 16384
#define EP_TILES 8      // 64-edge tiles per fusepool block
#define KE 224          // extended K: 192 PE + 16 feat + 16 zero-pad
#define XROWB 512       // bytes per A-row in LDS (256 bf16 cols, 32 chunks)

typedef __attribute__((ext_vector_type(8))) short bf16x8;
typedef __attribute__((ext_vector_type(4))) float f32x4;

__device__ __forceinline__ unsigned f2bf(float f) {
    unsigned x = __float_as_uint(f);
    return (x + 0x7fffu + ((x >> 16) & 1u)) >> 16;   // RNE
}
__device__ __forceinline__ float bf2f(unsigned short u) {
    return __uint_as_float(((unsigned)u) << 16);
}
// tanh-form GELU folded into accumulator: acc += gelu(v).
// max dev from exact erf-GELU ~5e-4 (validated r4-r10, absmax 0.0156)
__device__ __forceinline__ void gelu_acc(float v, float& acc) {
    const float m   = v * fmaf(v * v, -0.1029392f, -2.3021178f);
    const float den = 1.f + exp2f(m);
    const float r   = __builtin_amdgcn_rcpf(den);
    acc = fmaf(v, r, acc);
}

// ---------------------------------------------------------------------------
// prep: WtE/WbE [192 n][224 k] bf16:
//   k<192: W1blk[k][n] (transposed);  k in 192..207: (Win@W1blk)[k-192][n];
//   k>=208: 0.   cvt[n]=bin@W1t;  cvb[n]=bin@W1b + b1.
// ---------------------------------------------------------------------------
__global__ void prep_kernel(const float* __restrict__ W1,
                            const float* __restrict__ Win,
                            const float* __restrict__ bin,
                            const float* __restrict__ b1,
                            unsigned short* __restrict__ WtE,
                            unsigned short* __restrict__ WbE,
                            float* __restrict__ cvt,
                            float* __restrict__ cvb)
{
    const int i = blockIdx.x * 256 + threadIdx.x;
    if (i < 86016) {
        const int m = i / 43008;           // 0 = top block, 1 = bottom block
        const int j = i % 43008;
        const int n = j / KE, k = j % KE;
        const float* Wblk = W1 + (size_t)m * HD * HD;
        float v = 0.f;
        if (k < HD) v = Wblk[k * HD + n];
        else if (k < HD + INF) {
            const int kk = k - HD;
            for (int c = 0; c < HD; ++c)
                v = fmaf(Win[kk * HD + c], Wblk[c * HD + n], v);
        }
        (m ? WbE : WtE)[n * KE + k] = (unsigned short)f2bf(v);
    } else if (i < 86400) {
        const int m = (i - 86016) / HD;
        const int n = (i - 86016) % HD;
        const float* Wblk = W1 + (size_t)m * HD * HD;
        float v = m ? b1[n] : 0.f;
        for (int c = 0; c < HD; ++c)
            v = fmaf(bin[c], Wblk[c * HD + n], v);
        (m ? cvb : cvt)[n] = v;
    }
}

// ---------------------------------------------------------------------------
// Shared A-tile builder (PE + feat, bf16, XOR-swizzled, row stride 512 B):
//   PE col c (c<192) of row n at chunk (c>>3)^(n&7), offset (c&7)*2
//   feat col 192+(l&3)*4.. at chunks 24/25 (pre-swz), same XOR
//   chunks 26,27 (pre-swz) zero-filled once (k 208..223)
// Wave w owns rows w*16..+15; lane l owns PE cols {l, l+64, l+128}.
// ---------------------------------------------------------------------------

// ---------------------------------------------------------------------------
// bcomp: b = bf16( [PE|feat][sup] @ WbE^T + cvb ) -> C rows (stride 384 elems)
// ---------------------------------------------------------------------------
__global__ __launch_bounds__(256, 2)
void bcomp_kernel(const float* __restrict__ feat,
                  const float* __restrict__ pos,
                  const int*   __restrict__ sup,
                  const unsigned short* __restrict__ WbE,  // [192 n][224 k]
                  const float* __restrict__ cvb,
                  unsigned short* __restrict__ outp)       // stride 384 elems
{
    __shared__ __align__(16) unsigned short xs[64 * 256];    // 32768 B
    __shared__ __align__(16) unsigned short dstg[64 * HD];   // 24576 B
    __shared__ float pos_s[4][48];
    __shared__ int nid[64];

    const int t = threadIdx.x, w = t >> 6, l = t & 63;

    if (t < 64) nid[t] = sup[blockIdx.x * 64 + t];

    bf16x8 bfr[3][7];
    #pragma unroll
    for (int ct = 0; ct < 3; ++ct) {
        const int col = w * 48 + ct * 16 + (l & 15);
        const unsigned short* wp = WbE + (size_t)col * KE + (l >> 4) * 8;
        #pragma unroll
        for (int ks = 0; ks < 7; ++ks)
            bfr[ct][ks] = *reinterpret_cast<const bf16x8*>(wp + ks * 32);
    }
    float ccol[3];
    #pragma unroll
    for (int ct = 0; ct < 3; ++ct) ccol[ct] = cvb[w * 48 + ct * 16 + (l & 15)];
    const float om = exp2f(-(float)(l & 31) * 0.41524101186098287f);
    const float phase = (l < 32) ? 0.f : 1.57079632679f;

    // zero-fill pad chunks (pre-swz 26,27) once
    if (t < 128) {
        const int row = t >> 1, ch = 26 + (t & 1);
        uint4 z = {0u, 0u, 0u, 0u};
        *reinterpret_cast<uint4*>((char*)xs + row * XROWB + ((ch ^ (row & 7)) * 16)) = z;
    }
    __syncthreads();   // nid ready

    // gather feat/pos + build A-tile
    {
        const int row = w * 16 + (l >> 2);
        const float4 fs = *reinterpret_cast<const float4*>(
            feat + (size_t)nid[row] * INF + (l & 3) * 4);
        const int k0 = HD + (l & 3) * 4, ch = k0 >> 3;
        ushort4 fb;
        fb.x = (unsigned short)f2bf(fs.x); fb.y = (unsigned short)f2bf(fs.y);
        fb.z = (unsigned short)f2bf(fs.z); fb.w = (unsigned short)f2bf(fs.w);
        *reinterpret_cast<ushort4*>(
            (char*)xs + row * XROWB + ((ch ^ (row & 7)) * 16) + (k0 & 7) * 2) = fb;
        if (l < 48) pos_s[w][l] = pos[(size_t)nid[w * 16 + l / 3] * 3 + (l % 3)];
    }
    for (int r = 0; r < 16; ++r) {
        const int n = w * 16 + r;
        #pragma unroll
        for (int d = 0; d < 3; ++d) {
            const float pe = __sinf(fmaf(pos_s[w][r * 3 + d], om, phase));
            const int c = l + 64 * d;
            *reinterpret_cast<unsigned short*>(
                (char*)xs + n * XROWB + (((c >> 3) ^ (n & 7)) * 16) + (c & 7) * 2) =
                (unsigned short)f2bf(pe);
        }
    }
    __syncthreads();

    f32x4 acc[4][3];
    #pragma unroll
    for (int rt = 0; rt < 4; ++rt)
        #pragma unroll
        for (int ct = 0; ct < 3; ++ct)
            acc[rt][ct] = (f32x4){0.f, 0.f, 0.f, 0.f};

    #pragma unroll
    for (int ks = 0; ks < 7; ++ks) {
        bf16x8 af[4];
        #pragma unroll
        for (int rt = 0; rt < 4; ++rt) {
            const int row = rt * 16 + (l & 15);
            const int p = (ks * 4 + (l >> 4)) ^ (l & 7);   // row&7 == l&7
            af[rt] = *reinterpret_cast<const bf16x8*>((char*)xs + row * XROWB + p * 16);
        }
        #pragma unroll
        for (int rt = 0; rt < 4; ++rt)
            #pragma unroll
            for (int ct = 0; ct < 3; ++ct)
                acc[rt][ct] = __builtin_amdgcn_mfma_f32_16x16x32_bf16(
                    af[rt], bfr[ct][ks], acc[rt][ct], 0, 0, 0);
    }

    // D (+cvb) -> dstg (stride 384 B, old swizzle), then coalesced store
    char* db = (char*)dstg;
    #pragma unroll
    for (int rt = 0; rt < 4; ++rt)
        #pragma unroll
        for (int ct = 0; ct < 3; ++ct) {
            const int col = w * 48 + ct * 16 + (l & 15);
            const int ch = col >> 3, off = col & 7;
            #pragma unroll
            for (int j = 0; j < 4; ++j) {
                const int row = rt * 16 + (l >> 4) * 4 + j;
                *reinterpret_cast<unsigned short*>(
                    db + row * 384 + ((ch ^ (row & 7)) * 16) + off * 2) =
                    (unsigned short)f2bf(acc[rt][ct][j] + ccol[ct]);
            }
        }
    __syncthreads();
    const size_t orow0 = (size_t)blockIdx.x * 64;
    #pragma unroll
    for (int q = 0; q < 6; ++q) {
        const int id = q * 64 + l;
        const int rid = id / 6, cc = id % 6;
        const int c = w * 6 + cc;
        const bf16x8 v = *reinterpret_cast<const bf16x8*>(
            db + rid * 384 + ((c ^ (rid & 7)) * 16));
        *reinterpret_cast<bf16x8*>(outp + (orow0 + rid) * 384 + c * 8) = v;
    }
}

// ---------------------------------------------------------------------------
// fusepool: per 64-edge tile (2 supernodes): gather feat/pos[src] -> A-tile
// (PE+feat, double-buffered) -> MFMA K=224 -> +cvt +b[s] -> gelu ->
// shfl_xor(16)+shfl_xor(32) 32-row column sum -> g[s] = part/32 (over C).
// One barrier per tile; COMPUTE(tt+1) interleaves with MFMA(tt) (disjoint bufs).
// ---------------------------------------------------------------------------
__global__ __launch_bounds__(256, 2)
void fusepool_kernel(const float* __restrict__ feat,
                     const float* __restrict__ pos,
                     const int* __restrict__ src_idx,
                     const unsigned short* __restrict__ WtE,  // [192 n][224 k]
                     const float* __restrict__ cvt,
                     const unsigned short* __restrict__ bC,   // bf16, stride 384 elems
                     float* __restrict__ g)                   // f32, stride 192 (same mem)
{
    __shared__ __align__(16) unsigned short xs[2][64 * 256]; // 65536 B
    __shared__ float pos_s[4][48];                           //   768 B
    __shared__ int sIdx[EP_TILES * 64];                      //  2048 B
    __shared__ unsigned short bs[EP_TILES * 2 * HD];         //  6144 B

    const int t = threadIdx.x, w = t >> 6, l = t & 63;

    // block-start staging: src indices + this block's 16 b-rows
    #pragma unroll
    for (int i = 0; i < (EP_TILES * 64) / 256; ++i)
        sIdx[t + i * 256] = src_idx[(size_t)blockIdx.x * (EP_TILES * 64) + t + i * 256];
    {
        const size_t srow0 = (size_t)blockIdx.x * (EP_TILES * 2);
        #pragma unroll
        for (int i = 0; i < 6; ++i) {
            const int idx = t + i * 256;
            const int r = idx / 96, c = idx % 96;
            reinterpret_cast<unsigned*>(bs)[idx] =
                *reinterpret_cast<const unsigned*>(bC + (srow0 + r) * 384 + c * 2);
        }
    }

    bf16x8 bfr[3][7];
    #pragma unroll
    for (int ct = 0; ct < 3; ++ct) {
        const int col = w * 48 + ct * 16 + (l & 15);
        const unsigned short* wp = WtE + (size_t)col * KE + (l >> 4) * 8;
        #pragma unroll
        for (int ks = 0; ks < 7; ++ks)
            bfr[ct][ks] = *reinterpret_cast<const bf16x8*>(wp + ks * 32);
    }
    float ccol[3];
    #pragma unroll
    for (int ct = 0; ct < 3; ++ct) ccol[ct] = cvt[w * 48 + ct * 16 + (l & 15)];
    const float om = exp2f(-(float)(l & 31) * 0.41524101186098287f);
    const float phase = (l < 32) ? 0.f : 1.57079632679f;

    // zero-fill pad chunks (pre-swz 26,27) in both buffers once
    if (t < 128) {
        const int row = t >> 1, ch = 26 + (t & 1);
        uint4 z = {0u, 0u, 0u, 0u};
        *reinterpret_cast<uint4*>((char*)&xs[0][0] + row * XROWB + ((ch ^ (row & 7)) * 16)) = z;
        *reinterpret_cast<uint4*>((char*)&xs[1][0] + row * XROWB + ((ch ^ (row & 7)) * 16)) = z;
    }
    __syncthreads();   // sIdx/bs ready

    auto LOADT = [&](int tile, float4& fs, float& ps) {
        const int nf = sIdx[tile * 64 + w * 16 + (l >> 2)];
        fs = *reinterpret_cast<const float4*>(feat + (size_t)nf * INF + (l & 3) * 4);
        if (l < 48) {
            const int np = sIdx[tile * 64 + w * 16 + l / 3];
            ps = pos[(size_t)np * 3 + (l % 3)];
        }
    };
    auto COMPUTE = [&](unsigned short* xbuf, float4 fs, float ps) {
        {   // feat part -> chunks 24/25 (pre-swz)
            const int row = w * 16 + (l >> 2);
            const int k0 = HD + (l & 3) * 4, ch = k0 >> 3;
            ushort4 fb;
            fb.x = (unsigned short)f2bf(fs.x); fb.y = (unsigned short)f2bf(fs.y);
            fb.z = (unsigned short)f2bf(fs.z); fb.w = (unsigned short)f2bf(fs.w);
            *reinterpret_cast<ushort4*>(
                (char*)xbuf + row * XROWB + ((ch ^ (row & 7)) * 16) + (k0 & 7) * 2) = fb;
        }
        if (l < 48) pos_s[w][l] = ps;
        for (int r = 0; r < 16; ++r) {
            const int n = w * 16 + r;
            #pragma unroll
            for (int d = 0; d < 3; ++d) {
                const float pe = __sinf(fmaf(pos_s[w][r * 3 + d], om, phase));
                const int c = l + 64 * d;
                *reinterpret_cast<unsigned short*>(
                    (char*)xbuf + n * XROWB + (((c >> 3) ^ (n & 7)) * 16) + (c & 7) * 2) =
                    (unsigned short)f2bf(pe);
            }
        }
    };

    // prologue
    float4 fstage; float pstage = 0.f;
    LOADT(0, fstage, pstage);
    COMPUTE(&xs[0][0], fstage, pstage);
    if (EP_TILES > 1) LOADT(1, fstage, pstage);

    #pragma unroll 1
    for (int tt = 0; tt < EP_TILES; ++tt) {
        __syncthreads();   // xs[tt&1] ready for all waves

        if (tt + 1 < EP_TILES) {
            COMPUTE(&xs[(tt + 1) & 1][0], fstage, pstage);
            if (tt + 2 < EP_TILES) LOADT(tt + 2, fstage, pstage);
        }

        f32x4 acc[4][3];
        #pragma unroll
        for (int rt = 0; rt < 4; ++rt)
            #pragma unroll
            for (int ct = 0; ct < 3; ++ct)
                acc[rt][ct] = (f32x4){0.f, 0.f, 0.f, 0.f};

        const char* xb = (const char*)&xs[tt & 1][0];
        #pragma unroll
        for (int ks = 0; ks < 7; ++ks) {
            bf16x8 af[4];
            #pragma unroll
            for (int rt = 0; rt < 4; ++rt) {
                const int row = rt * 16 + (l & 15);
                const int p = (ks * 4 + (l >> 4)) ^ (l & 7);   // row&7 == l&7
                af[rt] = *reinterpret_cast<const bf16x8*>(xb + row * XROWB + p * 16);
            }
            #pragma unroll
            for (int rt = 0; rt < 4; ++rt)
                #pragma unroll
                for (int ct = 0; ct < 3; ++ct)
                    acc[rt][ct] = __builtin_amdgcn_mfma_f32_16x16x32_bf16(
                        af[rt], bfr[ct][ks], acc[rt][ct], 0, 0, 0);
        }

        // epilogue: +cvt +b (LDS), gelu, 32-row column reduce, store g
        const int s0l = tt * 2;
        #pragma unroll
        for (int sn = 0; sn < 2; ++sn)
            #pragma unroll
            for (int ct = 0; ct < 3; ++ct) {
                const float bv = ccol[ct] +
                    bf2f(bs[(s0l + sn) * HD + w * 48 + ct * 16 + (l & 15)]);
                float part = 0.f;
                #pragma unroll
                for (int r2 = 0; r2 < 2; ++r2)
                    #pragma unroll
                    for (int j = 0; j < 4; ++j)
                        gelu_acc(acc[sn * 2 + r2][ct][j] + bv, part);
                part += __shfl_xor(part, 16);
                part += __shfl_xor(part, 32);
                if (l < 16)
                    g[((size_t)blockIdx.x * (EP_TILES * 2) + s0l + sn) * HD +
                      w * 48 + ct * 16 + l] = part * 0.03125f;
            }
    }
}

// ---------------------------------------------------------------------------
// out = A[rows,192] @ W[192,192] + bias   (f32)
// ---------------------------------------------------------------------------
__global__ __launch_bounds__(256, 2)
void gemm192_kernel(const float* __restrict__ A,
                    const float* __restrict__ W,
                    const float* __restrict__ bias,
                    float* __restrict__ out)
{
    __shared__ float xsf[64][196];
    __shared__ float wchunk[32][HD];
    const int t    = threadIdx.x;
    const int row0 = blockIdx.x * 64;

    const float4* ap = reinterpret_cast<const float4*>(A + (size_t)row0 * HD);
    #pragma unroll
    for (int q = 0; q < 12; ++q) {
        const int f4 = t + q * 256;
        const int r = f4 / 48, c = f4 % 48;
        *reinterpret_cast<float4*>(&xsf[r][c * 4]) = ap[f4];
    }

    const int tr = t >> 4;
    const int tc = t & 15;
    float acc[4][12];
    #pragma unroll
    for (int i = 0; i < 4; ++i)
        #pragma unroll
        for (int j = 0; j < 12; ++j) acc[i][j] = 0.f;

    for (int kc = 0; kc < 6; ++kc) {
        __syncthreads();
        {
            const float4* wp = reinterpret_cast<const float4*>(W + kc * 32 * HD);
            float4* wsp = reinterpret_cast<float4*>(&wchunk[0][0]);
            #pragma unroll
            for (int q = 0; q < 6; ++q) wsp[t + q * 256] = wp[t + q * 256];
        }
        __syncthreads();
        #pragma unroll 4
        for (int k = 0; k < 32; ++k) {
            const int kg = kc * 32 + k;
            float xv[4];
            #pragma unroll
            for (int i = 0; i < 4; ++i) xv[i] = xsf[tr * 4 + i][kg];
            float wv[12];
            #pragma unroll
            for (int j4 = 0; j4 < 3; ++j4)
                *reinterpret_cast<float4*>(&wv[j4 * 4]) =
                    *reinterpret_cast<const float4*>(&wchunk[k][tc * 12 + j4 * 4]);
            #pragma unroll
            for (int i = 0; i < 4; ++i)
                #pragma unroll
                for (int j = 0; j < 12; ++j)
                    acc[i][j] = fmaf(xv[i], wv[j], acc[i][j]);
        }
    }

    float bb[12];
    #pragma unroll
    for (int j = 0; j < 12; ++j) bb[j] = bias[tc * 12 + j];

    #pragma unroll
    for (int i = 0; i < 4; ++i) {
        float* o = out + (size_t)(row0 + tr * 4 + i) * HD + tc * 12;
        #pragma unroll
        for (int j4 = 0; j4 < 3; ++j4) {
            float4 v;
            v.x = acc[i][j4 * 4 + 0] + bb[j4 * 4 + 0];
            v.y = acc[i][j4 * 4 + 1] + bb[j4 * 4 + 1];
            v.z = acc[i][j4 * 4 + 2] + bb[j4 * 4 + 2];
            v.w = acc[i][j4 * 4 + 3] + bb[j4 * 4 + 3];
            *reinterpret_cast<float4*>(o + j4 * 4) = v;
        }
    }
}

extern "C" void kernel_launch(void* const* d_in, const int* in_sizes, int n_in,
                              void* d_out, int out_size, void* d_ws, size_t ws_size,
                              hipStream_t stream)
{
    const float* feat = (const float*)d_in[0];
    const float* pos  = (const float*)d_in[1];
    const int*   sup  = (const int*)d_in[2];
    const int*   src  = (const int*)d_in[4];
    const float* Win  = (const float*)d_in[6];
    const float* bin  = (const float*)d_in[7];
    const float* W1   = (const float*)d_in[8];   // [384,192]
    const float* b1   = (const float*)d_in[9];
    const float* W2   = (const float*)d_in[10];  // [192,192]
    const float* b2   = (const float*)d_in[11];

    char* ws = (char*)d_ws;
    unsigned short* WtE = (unsigned short*)ws;               //  86016 B
    unsigned short* WbE = (unsigned short*)(ws + 86016);     //  86016 B
    float*          cvt = (float*)(ws + 172032);             //    768 B
    float*          cvb = (float*)(ws + 172800);             //    768 B
    char*           C   = ws + 173568;                       // 12582912 B
    float* out = (float*)d_out;

    prep_kernel<<<338, 256, 0, stream>>>(W1, Win, bin, b1, WtE, WbE, cvt, cvb);
    // b rows -> C (bf16, stride 384 elems)
    bcomp_kernel<<<N_SUP / 64, 256, 0, stream>>>(
        feat, pos, sup, WbE, cvb, (unsigned short*)C);
    // g = segment-mean(gelu(a_edge + b)) -> f32 in place over C
    fusepool_kernel<<<N_SUP / (2 * EP_TILES), 256, 0, stream>>>(
        feat, pos, src, WtE, cvt, (const unsigned short*)C, (float*)C);
    // out = g @ W2 + b2
    gemm192_kernel<<<N_SUP / 64, 256, 0, stream>>>((const float*)C, W2, b2, out);
}